// Round 8
// baseline (668.937 us; speedup 1.0000x reference)
//
#include <hip/hip_runtime.h>

typedef _Float16 half_t;
typedef _Float16 f16x8 __attribute__((ext_vector_type(8)));
typedef _Float16 f16x4 __attribute__((ext_vector_type(4)));
typedef float    f32x4 __attribute__((ext_vector_type(4)));
typedef float    f32x16 __attribute__((ext_vector_type(16)));

typedef const __attribute__((address_space(1))) void cg_void;
typedef __attribute__((address_space(3))) void lds_void;

#define BB 32
#define LP 2048
#define LQ 512
#define HH 1024

enum { M_QPROJ = 0, M_OUT32 = 1 };

// ---------------- generic f32 -> f16 (count = grid*1024) ----------------
__global__ void cvt16_k(const float* __restrict__ w, half_t* __restrict__ o) {
  long i = ((long)blockIdx.x * 256 + threadIdx.x) * 4;
  f32x4 v = *(const f32x4*)(w + i);
  f16x4 h;
  h[0] = (half_t)v[0]; h[1] = (half_t)v[1]; h[2] = (half_t)v[2]; h[3] = (half_t)v[3];
  *(f16x4*)(o + i) = h;
}

// ------------- dual cvt: f32 [z][R][C] -> rm f16 [z][R][C] + tr f16 [z][C][R] -------------
__global__ __launch_bounds__(256) void dualcvt_k(const float* __restrict__ in,
                                                 half_t* __restrict__ rm,
                                                 half_t* __restrict__ tr,
                                                 int R, int C) {
  __shared__ half_t tile[64 * 64];
  const long zb = blockIdx.z;
  const float* src = in + zb * (long)R * C;
  half_t* dstT = tr + zb * (long)C * R;
  half_t* dstR = rm + zb * (long)R * C;
  const int r0 = blockIdx.y * 64, c0 = blockIdx.x * 64;
  const int t = threadIdx.x;
  const int cl = (t & 15) * 4;
  const int rl = t >> 4;
#pragma unroll
  for (int rr = 0; rr < 4; rr++) {
    int r = rr * 16 + rl;
    f32x4 v = *(const f32x4*)(src + (long)(r0 + r) * C + c0 + cl);
    f16x4 h;
#pragma unroll
    for (int j = 0; j < 4; j++) {
      h[j] = (half_t)v[j];
      int c = cl + j;
      tile[c * 64 + (r ^ (((c >> 3) & 7) << 3))] = h[j];
    }
    *(f16x4*)(dstR + (long)(r0 + r) * C + c0 + cl) = h;
  }
  __syncthreads();
  const int c = t >> 2;
  const int rch = (t & 3) * 16;
  const int m = (c >> 3) & 7;
  const int B0 = c * 64 + (rch ^ ((m << 3) & 48));
  const int hi = (m & 1) << 3;
  f16x8 g0 = *(const f16x8*)&tile[B0 + hi];
  f16x8 g1 = *(const f16x8*)&tile[B0 + (8 ^ hi)];
  half_t* dp = dstT + (long)(c0 + c) * R + r0 + rch;
  *(f16x8*)dp = g0;
  *(f16x8*)(dp + 8) = g1;
}

// ------------- col-softmax scale table: stf[b][pt][q] = exp(pmg-cmax)*cinv (f16) -------------
__global__ __launch_bounds__(256) void stf_k(const float* __restrict__ pmg,
                                             const float* __restrict__ psg,
                                             half_t* __restrict__ stf) {
  long i = (long)blockIdx.x * 256 + threadIdx.x;  // b*LQ + q
  long b = i >> 9, q = i & 511;
  const float* mp = pmg + (b * 16) * LQ + q;
  const float* sp = psg + (b * 16) * LQ + q;
  float mv[16];
  float m = -3e38f, s = 0.f;
#pragma unroll
  for (int t = 0; t < 16; t++) {
    float mm = mp[(long)t * LQ]; mv[t] = mm;
    float ss = sp[(long)t * LQ];
    float nm = fmaxf(m, mm);
    s = s * __expf(m - nm) + ss * __expf(mm - nm);
    m = nm;
  }
  float inv = 1.f / s;
#pragma unroll
  for (int t = 0; t < 16; t++)
    stf[(b * 16 + t) * LQ + q] = (half_t)(__expf(mv[t] - m) * inv);
}

// ---------------- staging: [ROWS][32] f16 via gload_lds; k-slot XOR (row>>1)&3 ----------------
template<int ROWS>
__device__ __forceinline__ void stage_op(const half_t* src, int ld,
                                         half_t* lds_base, int wid, int lane) {
  const int goff = (((lane & 3) ^ ((lane >> 3) & 3)) << 3);
#pragma unroll
  for (int j = 0; j < ROWS / 128; ++j) {
    int row = j * 128 + wid * 16 + (lane >> 2);
    const half_t* g = src + (long)row * ld + goff;
    __builtin_amdgcn_global_load_lds((cg_void*)g,
        (lds_void*)(lds_base + j * 4096 + wid * 512), 16, 0, 0);
  }
}

__device__ __forceinline__ void xcd_swz(long lid, long nwg, long& out) {
  const long q8 = nwg >> 3, r8 = nwg & 7;
  const long xcd = lid & 7, rest = lid >> 3;
  out = (xcd < r8 ? xcd * (q8 + 1) : r8 * (q8 + 1) + (xcd - r8) * q8) + rest;
}

__device__ __forceinline__ f16x8 sc8(f16x8 v, half_t s) {
  f16x8 r;
#pragma unroll
  for (int j = 0; j < 8; ++j) r[j] = v[j] * s;
  return r;
}

// ---------------- fused att GEMM (32x32x16) + dual softmax prep ----------------
// 128x512 tile (full LQ), 8 waves 2x4, 3 LDS buffers, counted vmcnt.
// Outputs: Pp (row-softmax, f16), Et = E^T [LQ][LP] (exp vs tile-colmax, f16),
// col partials pmg/psg.
__global__ __launch_bounds__(512, 2) void attf_k(
    const half_t* __restrict__ Ap,   // p16 [B][LP][HH]
    const half_t* __restrict__ Bp,   // qpj16 [B][LQ][HH]
    half_t* __restrict__ PpO,        // [B][LP][LQ]
    half_t* __restrict__ Et,         // [B][LQ][LP]
    float* __restrict__ pmg, float* __restrict__ psg) {
  __shared__ __align__(16) half_t As[3 * 4096];
  __shared__ __align__(16) half_t Bs[3 * 16384];
  __shared__ float rmL[4][128];
  __shared__ float cmL[2][512];
  __shared__ float rsL[4][128];
  __shared__ float csL[2][512];

  const int nby = gridDim.y;  // 16
  long lid;
  xcd_swz(blockIdx.y + (long)nby * blockIdx.z, (long)nby * gridDim.z, lid);
  const int by = (int)(lid % nby);
  const int bz = (int)(lid / nby);

  const int t0 = threadIdx.x;
  const int lane = t0 & 63;
  const int wid = t0 >> 6;
  const int wm = wid >> 2, wn = wid & 3;
  const int m0 = by * 128;

  const half_t* Abase = Ap + ((long)bz * LP + m0) * HH;
  const half_t* Bbase = Bp + (long)bz * LQ * HH;

  const int c5 = lane & 31, hi = lane >> 5;
  const int sx = (c5 >> 1) & 3;
  const int ofs0 = c5 * 32 + ((hi ^ sx) << 3);
  const int ofs1 = c5 * 32 + (((2 | hi) ^ sx) << 3);

  f32x16 acc[2][4] = {};
  const int NT = HH / 32;   // 32

#pragma unroll
  for (int tt = 0; tt < 2; ++tt) {
    stage_op<128>(Abase + tt * 32, HH, As + tt * 4096, wid, lane);
    stage_op<512>(Bbase + tt * 32, HH, Bs + tt * 16384, wid, lane);
  }

  for (int t = 0; t < NT; ++t) {
    if (t + 1 < NT) asm volatile("s_waitcnt vmcnt(5)" ::: "memory");
    else            asm volatile("s_waitcnt vmcnt(0)" ::: "memory");
    __builtin_amdgcn_s_barrier();
    asm volatile("" ::: "memory");

    const half_t* Au = As + (t % 3) * 4096;
    const half_t* Bu = Bs + (t % 3) * 16384;
    f16x8 af[2][2], bf[4][2];
#pragma unroll
    for (int mf = 0; mf < 2; ++mf) {
      const half_t* p = Au + (wm * 64 + mf * 32) * 32;
      af[mf][0] = *(const f16x8*)(p + ofs0);
      af[mf][1] = *(const f16x8*)(p + ofs1);
    }
#pragma unroll
    for (int nf = 0; nf < 4; ++nf) {
      const half_t* p = Bu + (wn * 128 + nf * 32) * 32;
      bf[nf][0] = *(const f16x8*)(p + ofs0);
      bf[nf][1] = *(const f16x8*)(p + ofs1);
    }
    if (t + 2 < NT) {
      const int u2 = (t + 2) % 3;
      stage_op<128>(Abase + (t + 2) * 32, HH, As + u2 * 4096, wid, lane);
      stage_op<512>(Bbase + (t + 2) * 32, HH, Bs + u2 * 16384, wid, lane);
    }
    __builtin_amdgcn_s_setprio(1);
#pragma unroll
    for (int mf = 0; mf < 2; ++mf)
#pragma unroll
      for (int nf = 0; nf < 4; ++nf) {
        acc[mf][nf] = __builtin_amdgcn_mfma_f32_32x32x16_f16(af[mf][0], bf[nf][0], acc[mf][nf], 0, 0, 0);
        acc[mf][nf] = __builtin_amdgcn_mfma_f32_32x32x16_f16(af[mf][1], bf[nf][1], acc[mf][nf], 0, 0, 0);
      }
    __builtin_amdgcn_s_setprio(0);
  }

  // ===== pass1: row max (512 cols) / col max (128 rows); pmg write =====
  float rmv[2][16], cmv[4];
#pragma unroll
  for (int m = 0; m < 2; ++m)
#pragma unroll
    for (int r = 0; r < 16; ++r) {
      float v = fmaxf(fmaxf(acc[m][0][r], acc[m][1][r]), fmaxf(acc[m][2][r], acc[m][3][r]));
#pragma unroll
      for (int o = 1; o < 32; o <<= 1) v = fmaxf(v, __shfl_xor(v, o, 64));
      rmv[m][r] = v;
    }
#pragma unroll
  for (int n = 0; n < 4; ++n) {
    float v = acc[0][n][0];
#pragma unroll
    for (int m = 0; m < 2; ++m)
#pragma unroll
      for (int r = 0; r < 16; ++r) v = fmaxf(v, acc[m][n][r]);
    v = fmaxf(v, __shfl_xor(v, 32, 64));
    cmv[n] = v;
  }
  if (c5 < 16) {
#pragma unroll
    for (int m = 0; m < 2; ++m)
      rmL[wn][wm * 64 + m * 32 + (c5 & 3) + 8 * (c5 >> 2) + 4 * hi] = rmv[m][c5];
  }
  if (hi == 0) {
#pragma unroll
    for (int n = 0; n < 4; ++n) cmL[wm][wn * 128 + n * 32 + c5] = cmv[n];
  }
  __syncthreads();
  if (t0 < 128)
    rmL[0][t0] = fmaxf(fmaxf(rmL[0][t0], rmL[1][t0]), fmaxf(rmL[2][t0], rmL[3][t0]));
  {
    float cm2 = fmaxf(cmL[0][t0 & 511], cmL[1][t0 & 511]);
    cmL[0][t0 & 511] = cm2;
    pmg[((long)bz * 16 + by) * LQ + (t0 & 511)] = cm2;
  }
  __syncthreads();
#pragma unroll
  for (int m = 0; m < 2; ++m)
#pragma unroll
    for (int r = 0; r < 16; ++r)
      rmv[m][r] = rmL[0][wm * 64 + m * 32 + (r & 3) + 8 * (r >> 2) + 4 * hi];
#pragma unroll
  for (int n = 0; n < 4; ++n) cmv[n] = cmL[0][wn * 128 + n * 32 + c5];

  // ===== pass2: exps; pack p (slots 0..7) and e (slots 8..15) pairs into acc =====
  float rowS[2][16];
#pragma unroll
  for (int m = 0; m < 2; ++m)
#pragma unroll
    for (int r = 0; r < 16; ++r) rowS[m][r] = 0.f;
  float csW[4] = {0.f, 0.f, 0.f, 0.f};
#pragma unroll
  for (int m = 0; m < 2; ++m)
#pragma unroll
    for (int n = 0; n < 4; ++n) {
      float tp[16], te[16];
#pragma unroll
      for (int r = 0; r < 16; ++r) {
        float a = acc[m][n][r];
        float p = __expf(a - rmv[m][r]);
        float e = __expf(a - cmv[n]);
        rowS[m][r] += p;
        csW[n] += e;
        tp[r] = p; te[r] = e;
      }
#pragma unroll
      for (int j = 0; j < 8; ++j) {
        union { _Float16 h[2]; float f; } up, ue;
        up.h[0] = (half_t)tp[2 * j]; up.h[1] = (half_t)tp[2 * j + 1];
        ue.h[0] = (half_t)te[2 * j]; ue.h[1] = (half_t)te[2 * j + 1];
        acc[m][n][j] = up.f;
        acc[m][n][8 + j] = ue.f;
      }
    }
#pragma unroll
  for (int m = 0; m < 2; ++m)
#pragma unroll
    for (int r = 0; r < 16; ++r) {
      float s = rowS[m][r];
#pragma unroll
      for (int o = 1; o < 32; o <<= 1) s += __shfl_xor(s, o, 64);
      rowS[m][r] = s;
    }
#pragma unroll
  for (int n = 0; n < 4; ++n) csW[n] += __shfl_xor(csW[n], 32, 64);
  if (c5 < 16) {
#pragma unroll
    for (int m = 0; m < 2; ++m)
      rsL[wn][wm * 64 + m * 32 + (c5 & 3) + 8 * (c5 >> 2) + 4 * hi] = rowS[m][c5];
  }
  if (hi == 0) {
#pragma unroll
    for (int n = 0; n < 4; ++n) csL[wm][wn * 128 + n * 32 + c5] = csW[n];
  }
  __syncthreads();
  if (t0 < 128)
    rsL[0][t0] = 1.f / (rsL[0][t0] + rsL[1][t0] + rsL[2][t0] + rsL[3][t0]);
  psg[((long)bz * 16 + by) * LQ + (t0 & 511)] = csL[0][t0 & 511] + csL[1][t0 & 511];
  __syncthreads();

  // ===== pass3: Pp = p * rinv =====
  half_t* PpB = PpO + (long)bz * LP * LQ;
#pragma unroll
  for (int m = 0; m < 2; ++m)
#pragma unroll
    for (int j = 0; j < 8; ++j) {
      int r0a = 2 * j, r1a = 2 * j + 1;
      int row0 = wm * 64 + m * 32 + (r0a & 3) + 8 * (r0a >> 2) + 4 * hi;
      int row1 = wm * 64 + m * 32 + (r1a & 3) + 8 * (r1a >> 2) + 4 * hi;
      float ri0 = rsL[0][row0], ri1 = rsL[0][row1];
#pragma unroll
      for (int n = 0; n < 4; ++n) {
        union { _Float16 h[2]; float f; } u; u.f = acc[m][n][j];
        int col = wn * 128 + n * 32 + c5;
        PpB[(long)(m0 + row0) * LQ + col] = (half_t)((float)u.h[0] * ri0);
        PpB[(long)(m0 + row1) * LQ + col] = (half_t)((float)u.h[1] * ri1);
      }
    }

  // ===== pass4: E^T via LDS transpose rounds (reuse Bs as [128q][128p] tile) =====
  half_t* TQ = Bs;
  half_t* EtB = Et + (long)bz * LQ * LP;
#pragma unroll
  for (int rr2 = 0; rr2 < 4; ++rr2) {
    __syncthreads();
    if (wn == rr2) {
#pragma unroll
      for (int m = 0; m < 2; ++m)
#pragma unroll
        for (int n = 0; n < 4; ++n)
#pragma unroll
          for (int g = 0; g < 4; ++g) {
            int q_l = n * 32 + c5;
            int pblk = wm * 8 + m * 4 + g;
            int ah = q_l * 128 + ((pblk ^ (q_l & 7)) << 3) + 4 * hi;
            union { float f[2]; f16x4 h4; } u;
            u.f[0] = acc[m][n][8 + 2 * g];
            u.f[1] = acc[m][n][8 + 2 * g + 1];
            *(f16x4*)&TQ[ah] = u.h4;
          }
    }
    __syncthreads();
    {
      int q_l = t0 >> 2;
#pragma unroll
      for (int i2 = 0; i2 < 4; ++i2) {
        int pc = (t0 & 3) + 4 * i2;
        f16x8 v = *(const f16x8*)&TQ[q_l * 128 + ((pc ^ (q_l & 7)) << 3)];
        *(f16x8*)&EtB[(long)(rr2 * 128 + q_l) * LP + m0 + pc * 8] = v;
      }
    }
  }
}

// ---------------- pipelined TN MFMA GEMM (32x32x16), BMx256 tile ----------------
template<int MODE, int BM>
__global__ __launch_bounds__(512, 2) void gemm_k(
    const half_t* __restrict__ Ap, const half_t* __restrict__ Bp, void* __restrict__ Cp,
    const float* __restrict__ bias,
    int lda, int ldb, int ldc, int K,
    long sA, long sB, long sC) {
  constexpr int NMF = BM / 64;
  constexpr int AS = BM * 32;
  __shared__ __align__(16) half_t As[4 * AS];
  __shared__ __align__(16) half_t Bs[4 * 8192];

  const int nbx = gridDim.x, nby = gridDim.y;
  long lid;
  xcd_swz(blockIdx.x + (long)nbx * (blockIdx.y + (long)nby * blockIdx.z),
          (long)nbx * nby * gridDim.z, lid);
  const int bx = (int)(lid % nbx);
  const long tmp = lid / nbx;
  const int by = (int)(tmp % nby);
  const int bz = (int)(tmp / nby);

  const int t0 = threadIdx.x;
  const int lane = t0 & 63;
  const int wid = t0 >> 6;
  const int wm = wid >> 2, wn = wid & 3;
  const int m0 = by * BM, n0 = bx * 256;

  const half_t* Abase = Ap + sA * bz + (long)m0 * lda;
  const half_t* Bbase = Bp + sB * bz + (long)n0 * ldb;

  const int c5 = lane & 31, hi = lane >> 5;
  const int sx = (c5 >> 1) & 3;
  const int ofs0 = c5 * 32 + ((hi ^ sx) << 3);
  const int ofs1 = c5 * 32 + (((2 | hi) ^ sx) << 3);

  f32x16 acc[NMF][2] = {};
  const int NT = K >> 5;

#pragma unroll
  for (int tt = 0; tt < 3; ++tt) {
    stage_op<BM>(Abase + tt * 32, lda, As + tt * AS, wid, lane);
    stage_op<256>(Bbase + tt * 32, ldb, Bs + tt * 8192, wid, lane);
  }

  for (int t = 0; t < NT; ++t) {
    if (t + 2 < NT) {
      if constexpr (BM == 256) asm volatile("s_waitcnt vmcnt(8)" ::: "memory");
      else                     asm volatile("s_waitcnt vmcnt(6)" ::: "memory");
    } else if (t + 1 < NT) {
      if constexpr (BM == 256) asm volatile("s_waitcnt vmcnt(4)" ::: "memory");
      else                     asm volatile("s_waitcnt vmcnt(3)" ::: "memory");
    } else {
      asm volatile("s_waitcnt vmcnt(0)" ::: "memory");
    }
    __builtin_amdgcn_s_barrier();
    asm volatile("" ::: "memory");

    const half_t* Au = As + (t & 3) * AS;
    const half_t* Bu = Bs + (t & 3) * 8192;
    f16x8 af[NMF][2], bf[2][2];
#pragma unroll
    for (int mf = 0; mf < NMF; ++mf) {
      const half_t* p = Au + (wm * (BM / 2) + mf * 32) * 32;
      af[mf][0] = *(const f16x8*)(p + ofs0);
      af[mf][1] = *(const f16x8*)(p + ofs1);
    }
#pragma unroll
    for (int nf = 0; nf < 2; ++nf) {
      const half_t* p = Bu + (wn * 64 + nf * 32) * 32;
      bf[nf][0] = *(const f16x8*)(p + ofs0);
      bf[nf][1] = *(const f16x8*)(p + ofs1);
    }
    if (t + 3 < NT) {
      const int u3 = (t + 3) & 3;
      stage_op<BM>(Abase + (t + 3) * 32, lda, As + u3 * AS, wid, lane);
      stage_op<256>(Bbase + (t + 3) * 32, ldb, Bs + u3 * 8192, wid, lane);
    }
    __builtin_amdgcn_s_setprio(1);
#pragma unroll
    for (int mf = 0; mf < NMF; ++mf)
#pragma unroll
      for (int nf = 0; nf < 2; ++nf) {
        acc[mf][nf] = __builtin_amdgcn_mfma_f32_32x32x16_f16(af[mf][0], bf[nf][0], acc[mf][nf], 0, 0, 0);
        acc[mf][nf] = __builtin_amdgcn_mfma_f32_32x32x16_f16(af[mf][1], bf[nf][1], acc[mf][nf], 0, 0, 0);
      }
    __builtin_amdgcn_s_setprio(0);
  }

  // ---- epilogue: col=lane&31, row=(r&3)+8*(r>>2)+4*hi ----
#pragma unroll
  for (int nf = 0; nf < 2; ++nf) {
    int col = n0 + wn * 64 + nf * 32 + c5;
    float bv = 0.f;
    if constexpr (MODE == M_QPROJ) bv = bias[col];
#pragma unroll
    for (int mf = 0; mf < NMF; ++mf) {
      int rbase = m0 + wm * (BM / 2) + mf * 32 + 4 * hi;
#pragma unroll
      for (int r = 0; r < 16; ++r) {
        int row = rbase + (r & 3) + 8 * (r >> 2);
        if constexpr (MODE == M_QPROJ)
          ((half_t*)Cp)[(long)row * ldc + col] = (half_t)(acc[mf][nf][r] + bv);
        else
          ((float*)Cp)[sC * bz + (long)row * ldc + col] = acc[mf][nf][r];
      }
    }
  }
}

// ---------------- m_q GEMM: A = Et (reg-staged, fused Pq scale), B = pT16 ----------------
// 128(q) x 256(h) tile, K = LP = 2048. A dbuf LDS + counted B gload_lds pipeline.
__global__ __launch_bounds__(512, 2) void mqf_k(
    const half_t* __restrict__ Et,   // [B][LQ][LP]
    const half_t* __restrict__ Bp,   // pT16 [B][HH][LP]
    const half_t* __restrict__ stf,  // [B][16][LQ]
    float* __restrict__ Cp) {        // m_q [B][LQ][HH]
  __shared__ __align__(16) half_t Asb[2][128 * 32];
  __shared__ __align__(16) half_t Bsb[3][256 * 32];
  __shared__ half_t scL[16 * 128];

  const int nbx = gridDim.x, nby = gridDim.y;
  long lid;
  xcd_swz(blockIdx.x + (long)nbx * (blockIdx.y + (long)nby * blockIdx.z),
          (long)nbx * nby * gridDim.z, lid);
  const int bx = (int)(lid % nbx);
  const long tmp = lid / nbx;
  const int by = (int)(tmp % nby);
  const int bz = (int)(tmp / nby);

  const int t0 = threadIdx.x;
  const int lane = t0 & 63;
  const int wid = t0 >> 6;
  const int wm = wid >> 2, wn = wid & 3;
  const int q0 = by * 128, n0 = bx * 256;

  const half_t* Abase = Et + ((long)bz * LQ + q0) * LP;
  const half_t* Bbase = Bp + ((long)bz * HH + n0) * LP;

  if (t0 < 256) {
    f16x8 v = *(const f16x8*)(stf + ((long)bz * 16 + (t0 >> 4)) * LQ + q0 + (t0 & 15) * 8);
    *(f16x8*)&scL[(t0 >> 4) * 128 + (t0 & 15) * 8] = v;
  }
  __syncthreads();

  const int arow = t0 >> 2, aslot = t0 & 3;
  const int awoff = arow * 32 + ((aslot ^ ((arow >> 1) & 3)) << 3);
  const half_t* agp = Abase + (long)arow * LP + aslot * 8;

  const int c5 = lane & 31, hi = lane >> 5;
  const int sx = (c5 >> 1) & 3;
  const int ofs0 = c5 * 32 + ((hi ^ sx) << 3);
  const int ofs1 = c5 * 32 + (((2 | hi) ^ sx) << 3);

  f32x16 acc[2][2] = {};
  const int NT = LP / 32;  // 64

  // prologue: B0,B1 staged; A0,A1 to regs; A0 scaled+written
  stage_op<256>(Bbase + 0, LP, Bsb[0], wid, lane);
  stage_op<256>(Bbase + 32, LP, Bsb[1], wid, lane);
  f16x8 aA = *(const f16x8*)(agp + 0);
  f16x8 aB = *(const f16x8*)(agp + 32);
  *(f16x8*)&Asb[0][awoff] = sc8(aA, scL[arow]);   // pt(k=0) = 0
  asm volatile("s_waitcnt vmcnt(2)" ::: "memory");  // B0 definitely done

#define MQ_BODY(T, CURBUF, NXTBUF, USEREG, LOADREG)                            \
  {                                                                            \
    const int t = (T);                                                         \
    if (t + 1 < NT) asm volatile("s_waitcnt vmcnt(3) lgkmcnt(0)" ::: "memory");\
    else            asm volatile("s_waitcnt vmcnt(0) lgkmcnt(0)" ::: "memory");\
    __builtin_amdgcn_s_barrier();                                              \
    asm volatile("" ::: "memory");                                             \
    if (t + 2 < NT) {                                                          \
      stage_op<256>(Bbase + (t + 2) * 32, LP, Bsb[(t + 2) % 3], wid, lane);    \
      LOADREG = *(const f16x8*)(agp + (t + 2) * 32);                           \
    }                                                                          \
    const half_t* Au = Asb[CURBUF];                                            \
    const half_t* Bu = Bsb[t % 3];                                             \
    f16x8 af[2][2], bf[2][2];                                                  \
    _Pragma("unroll")                                                          \
    for (int mf = 0; mf < 2; ++mf) {                                           \
      const half_t* p = Au + (wm * 64 + mf * 32) * 32;                         \
      af[mf][0] = *(const f16x8*)(p + ofs0);                                   \
      af[mf][1] = *(const f16x8*)(p + ofs1);                                   \
    }                                                                          \
    _Pragma("unroll")                                                          \
    for (int nf = 0; nf < 2; ++nf) {                                           \
      const half_t* p = Bu + (wn * 64 + nf * 32) * 32;                         \
      bf[nf][0] = *(const f16x8*)(p + ofs0);                                   \
      bf[nf][1] = *(const f16x8*)(p + ofs1);                                   \
    }                                                                          \
    if (t + 1 < NT)                                                            \
      *(f16x8*)&Asb[NXTBUF][awoff] =                                           \
          sc8(USEREG, scL[((t + 1) >> 2) * 128 + arow]);                       \
    __builtin_amdgcn_s_setprio(1);                                             \
    _Pragma("unroll")                                                          \
    for (int mf = 0; mf < 2; ++mf)                                             \
      _Pragma("unroll")                                                        \
      for (int nf = 0; nf < 2; ++nf) {                                         \
        acc[mf][nf] = __builtin_amdgcn_mfma_f32_32x32x16_f16(af[mf][0], bf[nf][0], acc[mf][nf], 0, 0, 0); \
        acc[mf][nf] = __builtin_amdgcn_mfma_f32_32x32x16_f16(af[mf][1], bf[nf][1], acc[mf][nf], 0, 0, 0); \
      }                                                                        \
    __builtin_amdgcn_s_setprio(0);                                             \
  }

  for (int tt = 0; tt < NT; tt += 2) {
    MQ_BODY(tt,     0, 1, aB, aA)
    MQ_BODY(tt + 1, 1, 0, aA, aB)
  }
#undef MQ_BODY

#pragma unroll
  for (int nf = 0; nf < 2; ++nf) {
    int col = n0 + wn * 64 + nf * 32 + c5;
#pragma unroll
    for (int mf = 0; mf < 2; ++mf) {
      int rbase = q0 + wm * 64 + mf * 32 + 4 * hi;
#pragma unroll
      for (int r = 0; r < 16; ++r) {
        int row = rbase + (r & 3) + 8 * (r >> 2);
        Cp[(long)bz * LQ * HH + (long)row * HH + col] = acc[mf][nf][r];
      }
    }
  }
}

extern "C" void kernel_launch(void* const* d_in, const int* in_sizes, int n_in,
                              void* d_out, int out_size, void* d_ws, size_t ws_size,
                              hipStream_t stream) {
  const float* p_enc = (const float*)d_in[0];  // [B, LP, H]
  const float* q_enc = (const float*)d_in[1];  // [B, LQ, H]
  const float* Gw    = (const float*)d_in[2];  // [H, H]
  const float* Gb    = (const float*)d_in[3];  // [H]
  float* m_p = (float*)d_out;
  float* m_q = m_p + (long)BB * LP * HH;

  // workspace carve (~486 MB)
  half_t* w16   = (half_t*)d_ws;                    // HH*HH
  half_t* q16   = w16 + (long)HH * HH;              // BB*LQ*HH
  half_t* qT16  = q16 + (long)BB * LQ * HH;         // BB*HH*LQ
  half_t* qpj16 = qT16 + (long)BB * HH * LQ;        // BB*LQ*HH
  half_t* p16   = qpj16 + (long)BB * LQ * HH;       // BB*LP*HH
  half_t* pT16  = p16 + (long)BB * LP * HH;         // BB*HH*LP
  half_t* Pp    = pT16 + (long)BB * HH * LP;        // BB*LP*LQ
  half_t* Et    = Pp + (long)BB * LP * LQ;          // BB*LQ*LP
  half_t* stfb  = Et + (long)BB * LQ * LP;          // BB*16*LQ
  float*  pmg   = (float*)(stfb + (long)BB * 16 * LQ);  // BB*16*LQ
  float*  psg   = pmg + (long)BB * 16 * LQ;             // BB*16*LQ

  cvt16_k<<<HH * HH / 1024, 256, 0, stream>>>(Gw, w16);

  // q16 + qT16 (one read of q_enc)
  dualcvt_k<<<dim3(HH / 64, LQ / 64, BB), 256, 0, stream>>>(q_enc, q16, qT16, LQ, HH);

  // qproj16 = q16 . w16^T + Gb   (M=BB*LQ, N=HH, K=HH)
  gemm_k<M_QPROJ, 256><<<dim3(HH / 256, BB * LQ / 256, 1), 512, 0, stream>>>(
      q16, w16, qpj16, Gb, HH, HH, HH, HH, 0, 0, 0);

  // p16 + pT16 (one read of p_enc)
  dualcvt_k<<<dim3(HH / 64, LP / 64, BB), 256, 0, stream>>>(p_enc, p16, pT16, LP, HH);

  // fused att GEMM: Pp, E^T, col partials
  attf_k<<<dim3(1, LP / 128, BB), 512, 0, stream>>>(p16, qpj16, Pp, Et, pmg, psg);

  // col-softmax scale table
  stf_k<<<BB * LQ / 256, 256, 0, stream>>>(pmg, psg, stfb);

  // m_p = Pp @ qT16^T   (M=LP, N=HH, K=LQ)
  gemm_k<M_OUT32, 256><<<dim3(HH / 256, LP / 256, BB), 512, 0, stream>>>(
      Pp, qT16, m_p, nullptr, LQ, LQ, HH, LQ,
      (long)LP * LQ, (long)HH * LQ, (long)LP * HH);

  // m_q = (Et * stf) @ pT16^T   (M=LQ, N=HH, K=LP)
  mqf_k<<<dim3(HH / 256, LQ / 128, BB), 512, 0, stream>>>(Et, pT16, stfb, m_q);
}

// Round 9
// 646.044 us; speedup vs baseline: 1.0354x; 1.0354x over previous
//
#include <hip/hip_runtime.h>

typedef _Float16 half_t;
typedef _Float16 f16x8 __attribute__((ext_vector_type(8)));
typedef _Float16 f16x4 __attribute__((ext_vector_type(4)));
typedef float    f32x4 __attribute__((ext_vector_type(4)));
typedef float    f32x16 __attribute__((ext_vector_type(16)));

typedef const __attribute__((address_space(1))) void cg_void;
typedef __attribute__((address_space(3))) void lds_void;

#define BB 32
#define LP 2048
#define LQ 512
#define HH 1024

enum { M_QPROJ = 0, M_OUT32 = 1 };

// ---------------- generic f32 -> f16 (count = grid*1024) ----------------
__global__ void cvt16_k(const float* __restrict__ w, half_t* __restrict__ o) {
  long i = ((long)blockIdx.x * 256 + threadIdx.x) * 4;
  f32x4 v = *(const f32x4*)(w + i);
  f16x4 h;
  h[0] = (half_t)v[0]; h[1] = (half_t)v[1]; h[2] = (half_t)v[2]; h[3] = (half_t)v[3];
  *(f16x4*)(o + i) = h;
}

// ------------- dual cvt: f32 [z][R][C] -> rm f16 [z][R][C] + tr f16 [z][C][R] -------------
__global__ __launch_bounds__(256) void dualcvt_k(const float* __restrict__ in,
                                                 half_t* __restrict__ rm,
                                                 half_t* __restrict__ tr,
                                                 int R, int C) {
  __shared__ half_t tile[64 * 64];
  const long zb = blockIdx.z;
  const float* src = in + zb * (long)R * C;
  half_t* dstT = tr + zb * (long)C * R;
  half_t* dstR = rm + zb * (long)R * C;
  const int r0 = blockIdx.y * 64, c0 = blockIdx.x * 64;
  const int t = threadIdx.x;
  const int cl = (t & 15) * 4;
  const int rl = t >> 4;
#pragma unroll
  for (int rr = 0; rr < 4; rr++) {
    int r = rr * 16 + rl;
    f32x4 v = *(const f32x4*)(src + (long)(r0 + r) * C + c0 + cl);
    f16x4 h;
#pragma unroll
    for (int j = 0; j < 4; j++) {
      h[j] = (half_t)v[j];
      int c = cl + j;
      tile[c * 64 + (r ^ (((c >> 3) & 7) << 3))] = h[j];
    }
    *(f16x4*)(dstR + (long)(r0 + r) * C + c0 + cl) = h;
  }
  __syncthreads();
  const int c = t >> 2;
  const int rch = (t & 3) * 16;
  const int m = (c >> 3) & 7;
  const int B0 = c * 64 + (rch ^ ((m << 3) & 48));
  const int hi = (m & 1) << 3;
  f16x8 g0 = *(const f16x8*)&tile[B0 + hi];
  f16x8 g1 = *(const f16x8*)&tile[B0 + (8 ^ hi)];
  half_t* dp = dstT + (long)(c0 + c) * R + r0 + rch;
  *(f16x8*)dp = g0;
  *(f16x8*)(dp + 8) = g1;
}

// ---------------- finalize col stats from 16 per-m-tile partials ----------------
__global__ __launch_bounds__(256) void cfin_k(const float* __restrict__ pmg,
                                              const float* __restrict__ psg,
                                              float* __restrict__ cmax,
                                              float* __restrict__ cinv) {
  long i = (long)blockIdx.x * 256 + threadIdx.x;  // b*LQ + q
  long b = i / LQ, q = i - b * LQ;
  const float* mp = pmg + (b * 16) * LQ + q;
  const float* sp = psg + (b * 16) * LQ + q;
  float m = -3e38f, s = 0.f;
#pragma unroll
  for (int t = 0; t < 16; t++) {
    float mm = mp[(long)t * LQ], ss = sp[(long)t * LQ];
    float nm = fmaxf(m, mm);
    s = s * __expf(m - nm) + ss * __expf(mm - nm);
    m = nm;
  }
  cmax[i] = m;
  cinv[i] = 1.f / s;
}

// ------------- Pq from E: Pq[q][p] = E[p][q]*exp(pmg[tile][q]-cmax[q])*cinv[q] -------------
__global__ __launch_bounds__(256) void pq_k(const half_t* __restrict__ E,
                                            half_t* __restrict__ out,
                                            const float* __restrict__ pmg,
                                            const float* __restrict__ cmax,
                                            const float* __restrict__ cinv) {
  __shared__ half_t tile[64 * 64];
  const long zb = blockIdx.z;
  const half_t* src = E + zb * (long)LP * LQ;
  half_t* dst = out + zb * (long)LQ * LP;
  const int r0 = blockIdx.y * 64, c0 = blockIdx.x * 64;
  const int tIdx = r0 >> 7;
  const int t = threadIdx.x;
  const int cl = (t & 15) * 4;
  const int rl = t >> 4;
  f32x4 tm = *(const f32x4*)(pmg + ((long)zb * 16 + tIdx) * LQ + c0 + cl);
  f32x4 cm = *(const f32x4*)(cmax + (long)zb * LQ + c0 + cl);
  f32x4 ci = *(const f32x4*)(cinv + (long)zb * LQ + c0 + cl);
  float sc[4];
#pragma unroll
  for (int j = 0; j < 4; j++) sc[j] = __expf(tm[j] - cm[j]) * ci[j];
#pragma unroll
  for (int rr = 0; rr < 4; rr++) {
    int r = rr * 16 + rl;
    f16x4 v = *(const f16x4*)(src + (long)(r0 + r) * LQ + c0 + cl);
#pragma unroll
    for (int j = 0; j < 4; j++) {
      float x = (float)v[j] * sc[j];
      int c = cl + j;
      tile[c * 64 + (r ^ (((c >> 3) & 7) << 3))] = (half_t)x;
    }
  }
  __syncthreads();
  const int c = t >> 2;
  const int rch = (t & 3) * 16;
  const int m = (c >> 3) & 7;
  const int B0 = c * 64 + (rch ^ ((m << 3) & 48));
  const int hi = (m & 1) << 3;
  f16x8 g0 = *(const f16x8*)&tile[B0 + hi];
  f16x8 g1 = *(const f16x8*)&tile[B0 + (8 ^ hi)];
  half_t* dp = dst + (long)(c0 + c) * LP + r0 + rch;
  *(f16x8*)dp = g0;
  *(f16x8*)(dp + 8) = g1;
}

// ---------------- staging: [ROWS][32] f16 via gload_lds; k-slot XOR (row>>1)&3 ----------------
// store side: slot' = (lane&3) ^ ((row>>1)&3); row = j*128 + wid*16 + lane>>2
// => (row>>1)&3 == (lane>>3)&3  -> per-lane-constant global offset.
template<int ROWS>
__device__ __forceinline__ void stage_op(const half_t* src, int ld,
                                         half_t* lds_base, int wid, int lane) {
  const int goff = (((lane & 3) ^ ((lane >> 3) & 3)) << 3);
#pragma unroll
  for (int j = 0; j < ROWS / 128; ++j) {
    int row = j * 128 + wid * 16 + (lane >> 2);
    const half_t* g = src + (long)row * ld + goff;
    __builtin_amdgcn_global_load_lds((cg_void*)g,
        (lds_void*)(lds_base + j * 4096 + wid * 512), 16, 0, 0);
  }
}

__device__ __forceinline__ void xcd_swz(long lid, long nwg, long& out) {
  const long q8 = nwg >> 3, r8 = nwg & 7;
  const long xcd = lid & 7, rest = lid >> 3;
  out = (xcd < r8 ? xcd * (q8 + 1) : r8 * (q8 + 1) + (xcd - r8) * q8) + rest;
}

// ---------------- fused att GEMM (32x32x16) + dual softmax prep ----------------
// 128x512 tile (full LQ), 8 waves 2x4, 3 LDS buffers, counted vmcnt.
__global__ __launch_bounds__(512, 2) void attf_k(
    const half_t* __restrict__ Ap,   // p16 [B][LP][HH]
    const half_t* __restrict__ Bp,   // qpj16 [B][LQ][HH]
    half_t* __restrict__ PpO,        // [B][LP][LQ]
    half_t* __restrict__ EO,         // [B][LP][LQ]
    float* __restrict__ pmg, float* __restrict__ psg) {
  __shared__ __align__(16) half_t As[3 * 4096];
  __shared__ __align__(16) half_t Bs[3 * 16384];
  __shared__ float rmL[4][128];
  __shared__ float cmL[2][512];
  __shared__ float rsL[4][128];
  __shared__ float csL[2][512];

  const int nby = gridDim.y;  // 16
  long lid;
  xcd_swz(blockIdx.y + (long)nby * blockIdx.z, (long)nby * gridDim.z, lid);
  const int by = (int)(lid % nby);
  const int bz = (int)(lid / nby);

  const int t0 = threadIdx.x;
  const int lane = t0 & 63;
  const int wid = t0 >> 6;
  const int wm = wid >> 2, wn = wid & 3;
  const int m0 = by * 128;

  const half_t* Abase = Ap + ((long)bz * LP + m0) * HH;
  const half_t* Bbase = Bp + (long)bz * LQ * HH;

  const int c5 = lane & 31, hi = lane >> 5;
  const int sx = (c5 >> 1) & 3;
  const int ofs0 = c5 * 32 + ((hi ^ sx) << 3);
  const int ofs1 = c5 * 32 + (((2 | hi) ^ sx) << 3);

  f32x16 acc[2][4] = {};
  const int NT = HH / 32;   // 32

#pragma unroll
  for (int tt = 0; tt < 2; ++tt) {
    stage_op<128>(Abase + tt * 32, HH, As + tt * 4096, wid, lane);
    stage_op<512>(Bbase + tt * 32, HH, Bs + tt * 16384, wid, lane);
  }

  for (int t = 0; t < NT; ++t) {
    if (t + 1 < NT) asm volatile("s_waitcnt vmcnt(5)" ::: "memory");
    else            asm volatile("s_waitcnt vmcnt(0)" ::: "memory");
    __builtin_amdgcn_s_barrier();
    asm volatile("" ::: "memory");

    // stage first (T3 order): loads enter queue before ds_reads
    if (t + 2 < NT) {
      const int u2 = (t + 2) % 3;
      stage_op<128>(Abase + (t + 2) * 32, HH, As + u2 * 4096, wid, lane);
      stage_op<512>(Bbase + (t + 2) * 32, HH, Bs + u2 * 16384, wid, lane);
    }

    const half_t* Au = As + (t % 3) * 4096;
    const half_t* Bu = Bs + (t % 3) * 16384;
    f16x8 af[2][2], bf[4][2];
#pragma unroll
    for (int mf = 0; mf < 2; ++mf) {
      const half_t* p = Au + (wm * 64 + mf * 32) * 32;
      af[mf][0] = *(const f16x8*)(p + ofs0);
      af[mf][1] = *(const f16x8*)(p + ofs1);
    }
#pragma unroll
    for (int nf = 0; nf < 4; ++nf) {
      const half_t* p = Bu + (wn * 128 + nf * 32) * 32;
      bf[nf][0] = *(const f16x8*)(p + ofs0);
      bf[nf][1] = *(const f16x8*)(p + ofs1);
    }
    __builtin_amdgcn_s_setprio(1);
#pragma unroll
    for (int mf = 0; mf < 2; ++mf)
#pragma unroll
      for (int nf = 0; nf < 4; ++nf) {
        acc[mf][nf] = __builtin_amdgcn_mfma_f32_32x32x16_f16(af[mf][0], bf[nf][0], acc[mf][nf], 0, 0, 0);
        acc[mf][nf] = __builtin_amdgcn_mfma_f32_32x32x16_f16(af[mf][1], bf[nf][1], acc[mf][nf], 0, 0, 0);
      }
    __builtin_amdgcn_s_setprio(0);
  }

  // ===== pass1: row max (512 cols) / col max (128 rows); pmg write =====
  float rmv[2][16], cmv[4];
#pragma unroll
  for (int m = 0; m < 2; ++m)
#pragma unroll
    for (int r = 0; r < 16; ++r) {
      float v = fmaxf(fmaxf(acc[m][0][r], acc[m][1][r]), fmaxf(acc[m][2][r], acc[m][3][r]));
#pragma unroll
      for (int o = 1; o < 32; o <<= 1) v = fmaxf(v, __shfl_xor(v, o, 64));
      rmv[m][r] = v;
    }
#pragma unroll
  for (int n = 0; n < 4; ++n) {
    float v = acc[0][n][0];
#pragma unroll
    for (int m = 0; m < 2; ++m)
#pragma unroll
      for (int r = 0; r < 16; ++r) v = fmaxf(v, acc[m][n][r]);
    v = fmaxf(v, __shfl_xor(v, 32, 64));
    cmv[n] = v;
  }
  if (c5 < 16) {
#pragma unroll
    for (int m = 0; m < 2; ++m)
      rmL[wn][wm * 64 + m * 32 + (c5 & 3) + 8 * (c5 >> 2) + 4 * hi] = rmv[m][c5];
  }
  if (hi == 0) {
#pragma unroll
    for (int n = 0; n < 4; ++n) cmL[wm][wn * 128 + n * 32 + c5] = cmv[n];
  }
  __syncthreads();
  if (t0 < 128)
    rmL[0][t0] = fmaxf(fmaxf(rmL[0][t0], rmL[1][t0]), fmaxf(rmL[2][t0], rmL[3][t0]));
  {
    float cm2 = fmaxf(cmL[0][t0 & 511], cmL[1][t0 & 511]);
    cmL[0][t0 & 511] = cm2;
    pmg[((long)bz * 16 + by) * LQ + (t0 & 511)] = cm2;
  }
  __syncthreads();
#pragma unroll
  for (int m = 0; m < 2; ++m)
#pragma unroll
    for (int r = 0; r < 16; ++r)
      rmv[m][r] = rmL[0][wm * 64 + m * 32 + (r & 3) + 8 * (r >> 2) + 4 * hi];
#pragma unroll
  for (int n = 0; n < 4; ++n) cmv[n] = cmL[0][wn * 128 + n * 32 + c5];

  // ===== pass2 (merged): one exp pass -> E store + col sums + row sums; acc <- p =====
  half_t* EB = EO + (long)bz * LP * LQ;
  float csW[4] = {0.f, 0.f, 0.f, 0.f};
  float rowS[2][16];
#pragma unroll
  for (int m = 0; m < 2; ++m)
#pragma unroll
    for (int r = 0; r < 16; ++r) {
      long grow = (long)(m0 + wm * 64 + m * 32 + (r & 3) + 8 * (r >> 2) + 4 * hi) * LQ;
      float s = 0.f;
#pragma unroll
      for (int n = 0; n < 4; ++n) {
        float a = acc[m][n][r];
        float e = __expf(a - cmv[n]);
        float p = __expf(a - rmv[m][r]);
        csW[n] += e;
        EB[grow + wn * 128 + n * 32 + c5] = (half_t)e;
        acc[m][n][r] = p;
        s += p;
      }
#pragma unroll
      for (int o = 1; o < 32; o <<= 1) s += __shfl_xor(s, o, 64);
      rowS[m][r] = s;
    }
#pragma unroll
  for (int n = 0; n < 4; ++n) csW[n] += __shfl_xor(csW[n], 32, 64);
  if (c5 < 16) {
#pragma unroll
    for (int m = 0; m < 2; ++m)
      rsL[wn][wm * 64 + m * 32 + (c5 & 3) + 8 * (c5 >> 2) + 4 * hi] = rowS[m][c5];
  }
  if (hi == 0) {
#pragma unroll
    for (int n = 0; n < 4; ++n) csL[wm][wn * 128 + n * 32 + c5] = csW[n];
  }
  __syncthreads();
  if (t0 < 128)
    rsL[0][t0] = 1.f / (rsL[0][t0] + rsL[1][t0] + rsL[2][t0] + rsL[3][t0]);
  psg[((long)bz * 16 + by) * LQ + (t0 & 511)] = csL[0][t0 & 511] + csL[1][t0 & 511];
  __syncthreads();

  // ===== pass3: Pp = p * rinv =====
  half_t* PpB = PpO + (long)bz * LP * LQ;
#pragma unroll
  for (int m = 0; m < 2; ++m)
#pragma unroll
    for (int r = 0; r < 16; ++r) {
      int row = wm * 64 + m * 32 + (r & 3) + 8 * (r >> 2) + 4 * hi;
      long grow = (long)(m0 + row) * LQ;
      float ri = rsL[0][row];
#pragma unroll
      for (int n = 0; n < 4; ++n)
        PpB[grow + wn * 128 + n * 32 + c5] = (half_t)(acc[m][n][r] * ri);
    }
}

// ---------------- pipelined TN MFMA GEMM (32x32x16), BMx256 tile ----------------
template<int MODE, int BM>
__global__ __launch_bounds__(512, 2) void gemm_k(
    const half_t* __restrict__ Ap, const half_t* __restrict__ Bp, void* __restrict__ Cp,
    const float* __restrict__ bias,
    int lda, int ldb, int ldc, int K,
    long sA, long sB, long sC) {
  constexpr int NMF = BM / 64;
  constexpr int AS = BM * 32;
  __shared__ __align__(16) half_t As[4 * AS];
  __shared__ __align__(16) half_t Bs[4 * 8192];

  const int nbx = gridDim.x, nby = gridDim.y;
  long lid;
  xcd_swz(blockIdx.x + (long)nbx * (blockIdx.y + (long)nby * blockIdx.z),
          (long)nbx * nby * gridDim.z, lid);
  const int bx = (int)(lid % nbx);
  const long tmp = lid / nbx;
  const int by = (int)(tmp % nby);
  const int bz = (int)(tmp / nby);

  const int t0 = threadIdx.x;
  const int lane = t0 & 63;
  const int wid = t0 >> 6;
  const int wm = wid >> 2, wn = wid & 3;
  const int m0 = by * BM, n0 = bx * 256;

  const half_t* Abase = Ap + sA * bz + (long)m0 * lda;
  const half_t* Bbase = Bp + sB * bz + (long)n0 * ldb;

  const int c5 = lane & 31, hi = lane >> 5;
  const int sx = (c5 >> 1) & 3;
  const int ofs0 = c5 * 32 + ((hi ^ sx) << 3);
  const int ofs1 = c5 * 32 + (((2 | hi) ^ sx) << 3);

  f32x16 acc[NMF][2] = {};
  const int NT = K >> 5;

#pragma unroll
  for (int tt = 0; tt < 3; ++tt) {
    stage_op<BM>(Abase + tt * 32, lda, As + tt * AS, wid, lane);
    stage_op<256>(Bbase + tt * 32, ldb, Bs + tt * 8192, wid, lane);
  }

  for (int t = 0; t < NT; ++t) {
    // counted vmcnt: drain ONLY the oldest tile (6 or 5 loads/tile; two tiles stay in flight)
    if (t + 2 < NT) {
      if constexpr (BM == 256) asm volatile("s_waitcnt vmcnt(12)" ::: "memory");
      else                     asm volatile("s_waitcnt vmcnt(10)" ::: "memory");
    } else if (t + 1 < NT) {
      if constexpr (BM == 256) asm volatile("s_waitcnt vmcnt(6)" ::: "memory");
      else                     asm volatile("s_waitcnt vmcnt(5)" ::: "memory");
    } else {
      asm volatile("s_waitcnt vmcnt(0)" ::: "memory");
    }
    __builtin_amdgcn_s_barrier();
    asm volatile("" ::: "memory");

    // stage first (T3 order)
    if (t + 3 < NT) {
      const int u3 = (t + 3) & 3;
      stage_op<BM>(Abase + (t + 3) * 32, lda, As + u3 * AS, wid, lane);
      stage_op<256>(Bbase + (t + 3) * 32, ldb, Bs + u3 * 8192, wid, lane);
    }

    const half_t* Au = As + (t & 3) * AS;
    const half_t* Bu = Bs + (t & 3) * 8192;
    f16x8 af[NMF][2], bf[2][2];
#pragma unroll
    for (int mf = 0; mf < NMF; ++mf) {
      const half_t* p = Au + (wm * (BM / 2) + mf * 32) * 32;
      af[mf][0] = *(const f16x8*)(p + ofs0);
      af[mf][1] = *(const f16x8*)(p + ofs1);
    }
#pragma unroll
    for (int nf = 0; nf < 2; ++nf) {
      const half_t* p = Bu + (wn * 64 + nf * 32) * 32;
      bf[nf][0] = *(const f16x8*)(p + ofs0);
      bf[nf][1] = *(const f16x8*)(p + ofs1);
    }
    __builtin_amdgcn_s_setprio(1);
#pragma unroll
    for (int mf = 0; mf < NMF; ++mf)
#pragma unroll
      for (int nf = 0; nf < 2; ++nf) {
        acc[mf][nf] = __builtin_amdgcn_mfma_f32_32x32x16_f16(af[mf][0], bf[nf][0], acc[mf][nf], 0, 0, 0);
        acc[mf][nf] = __builtin_amdgcn_mfma_f32_32x32x16_f16(af[mf][1], bf[nf][1], acc[mf][nf], 0, 0, 0);
      }
    __builtin_amdgcn_s_setprio(0);
  }

  // ---- epilogue: col=lane&31, row=(r&3)+8*(r>>2)+4*hi ----
#pragma unroll
  for (int nf = 0; nf < 2; ++nf) {
    int col = n0 + wn * 64 + nf * 32 + c5;
    float bv = 0.f;
    if constexpr (MODE == M_QPROJ) bv = bias[col];
#pragma unroll
    for (int mf = 0; mf < NMF; ++mf) {
      int rbase = m0 + wm * (BM / 2) + mf * 32 + 4 * hi;
#pragma unroll
      for (int r = 0; r < 16; ++r) {
        int row = rbase + (r & 3) + 8 * (r >> 2);
        if constexpr (MODE == M_QPROJ)
          ((half_t*)Cp)[(long)row * ldc + col] = (half_t)(acc[mf][nf][r] + bv);
        else
          ((float*)Cp)[sC * bz + (long)row * ldc + col] = acc[mf][nf][r];
      }
    }
  }
}

extern "C" void kernel_launch(void* const* d_in, const int* in_sizes, int n_in,
                              void* d_out, int out_size, void* d_ws, size_t ws_size,
                              hipStream_t stream) {
  const float* p_enc = (const float*)d_in[0];  // [B, LP, H]
  const float* q_enc = (const float*)d_in[1];  // [B, LQ, H]
  const float* Gw    = (const float*)d_in[2];  // [H, H]
  const float* Gb    = (const float*)d_in[3];  // [H]
  float* m_p = (float*)d_out;
  float* m_q = m_p + (long)BB * LP * HH;

  // workspace carve (~548 MB, ws is ~1.25 GiB)
  half_t* w16   = (half_t*)d_ws;                    // HH*HH
  half_t* q16   = w16 + (long)HH * HH;              // BB*LQ*HH
  half_t* qT16  = q16 + (long)BB * LQ * HH;         // BB*HH*LQ
  half_t* qpj16 = qT16 + (long)BB * HH * LQ;        // BB*LQ*HH
  half_t* p16   = qpj16 + (long)BB * LQ * HH;       // BB*LP*HH
  half_t* pT16  = p16 + (long)BB * LP * HH;         // BB*HH*LP
  half_t* Pp    = pT16 + (long)BB * HH * LP;        // BB*LP*LQ
  half_t* Ebuf  = Pp + (long)BB * LP * LQ;          // BB*LP*LQ
  half_t* Pq    = Ebuf + (long)BB * LP * LQ;        // BB*LQ*LP
  float*  cmaxb = (float*)(Pq + (long)BB * LQ * LP);
  float*  cinvb = cmaxb + (long)BB * LQ;
  float*  pmg   = cinvb + (long)BB * LQ;            // BB*16*LQ
  float*  psg   = pmg + (long)BB * 16 * LQ;         // BB*16*LQ

  cvt16_k<<<HH * HH / 1024, 256, 0, stream>>>(Gw, w16);

  // q16 + qT16 (one read of q_enc)
  dualcvt_k<<<dim3(HH / 64, LQ / 64, BB), 256, 0, stream>>>(q_enc, q16, qT16, LQ, HH);

  // qproj16 = q16 . w16^T + Gb   (M=BB*LQ=16384, N=HH, K=HH)
  gemm_k<M_QPROJ, 256><<<dim3(HH / 256, BB * LQ / 256, 1), 512, 0, stream>>>(
      q16, w16, qpj16, Gb, HH, HH, HH, HH, 0, 0, 0);

  // p16 + pT16 (one read of p_enc)
  dualcvt_k<<<dim3(HH / 64, LP / 64, BB), 256, 0, stream>>>(p_enc, p16, pT16, LP, HH);

  // fused att GEMM: Pp, E, col partials
  attf_k<<<dim3(1, LP / 128, BB), 512, 0, stream>>>(p16, qpj16, Pp, Ebuf, pmg, psg);

  // finalize col stats; build Pq from E
  cfin_k<<<BB * LQ / 256, 256, 0, stream>>>(pmg, psg, cmaxb, cinvb);
  pq_k<<<dim3(LQ / 64, LP / 64, BB), 256, 0, stream>>>(Ebuf, Pq, pmg, cmaxb, cinvb);

  // m_p = Pp @ qT16^T   (M=LP, N=HH, K=LQ)
  gemm_k<M_OUT32, 256><<<dim3(HH / 256, LP / 256, BB), 512, 0, stream>>>(
      Pp, qT16, m_p, nullptr, LQ, LQ, HH, LQ,
      (long)LP * LQ, (long)HH * LQ, (long)LP * HH);

  // m_q = Pq @ pT16^T   (M=LQ, N=HH, K=LP)
  gemm_k<M_OUT32, 128><<<dim3(HH / 256, LQ / 128, BB), 512, 0, stream>>>(
      Pq, pT16, m_q, nullptr, LP, LP, HH, LP,
      (long)LQ * LP, (long)HH * LP, (long)LQ * HH);
}

// Round 10
// 535.417 us; speedup vs baseline: 1.2494x; 1.2066x over previous
//
#include <hip/hip_runtime.h>

typedef _Float16 half_t;
typedef _Float16 f16x8 __attribute__((ext_vector_type(8)));
typedef _Float16 f16x4 __attribute__((ext_vector_type(4)));
typedef float    f32x4 __attribute__((ext_vector_type(4)));
typedef float    f32x16 __attribute__((ext_vector_type(16)));

typedef const __attribute__((address_space(1))) void cg_void;
typedef __attribute__((address_space(3))) void lds_void;

#define BB 32
#define LP 2048
#define LQ 512
#define HH 1024

enum { M_QPROJ = 0, M_OUT32 = 1 };

// ---------------- generic f32 -> f16 (count = grid*1024) ----------------
__global__ void cvt16_k(const float* __restrict__ w, half_t* __restrict__ o) {
  long i = ((long)blockIdx.x * 256 + threadIdx.x) * 4;
  f32x4 v = *(const f32x4*)(w + i);
  f16x4 h;
  h[0] = (half_t)v[0]; h[1] = (half_t)v[1]; h[2] = (half_t)v[2]; h[3] = (half_t)v[3];
  *(f16x4*)(o + i) = h;
}

// ------------- dual cvt: f32 [z][R][C] -> rm f16 [z][R][C] + tr f16 [z][C][R] -------------
__global__ __launch_bounds__(256) void dualcvt_k(const float* __restrict__ in,
                                                 half_t* __restrict__ rm,
                                                 half_t* __restrict__ tr,
                                                 int R, int C) {
  __shared__ half_t tile[64 * 64];
  const long zb = blockIdx.z;
  const float* src = in + zb * (long)R * C;
  half_t* dstT = tr + zb * (long)C * R;
  half_t* dstR = rm + zb * (long)R * C;
  const int r0 = blockIdx.y * 64, c0 = blockIdx.x * 64;
  const int t = threadIdx.x;
  const int cl = (t & 15) * 4;
  const int rl = t >> 4;
#pragma unroll
  for (int rr = 0; rr < 4; rr++) {
    int r = rr * 16 + rl;
    f32x4 v = *(const f32x4*)(src + (long)(r0 + r) * C + c0 + cl);
    f16x4 h;
#pragma unroll
    for (int j = 0; j < 4; j++) {
      h[j] = (half_t)v[j];
      int c = cl + j;
      tile[c * 64 + (r ^ (((c >> 3) & 7) << 3))] = h[j];
    }
    *(f16x4*)(dstR + (long)(r0 + r) * C + c0 + cl) = h;
  }
  __syncthreads();
  const int c = t >> 2;
  const int rch = (t & 3) * 16;
  const int m = (c >> 3) & 7;
  const int B0 = c * 64 + (rch ^ ((m << 3) & 48));
  const int hi = (m & 1) << 3;
  f16x8 g0 = *(const f16x8*)&tile[B0 + hi];
  f16x8 g1 = *(const f16x8*)&tile[B0 + (8 ^ hi)];
  half_t* dp = dstT + (long)(c0 + c) * R + r0 + rch;
  *(f16x8*)dp = g0;
  *(f16x8*)(dp + 8) = g1;
}

// ---------------- finalize col stats from 16 per-m-tile partials ----------------
__global__ __launch_bounds__(256) void cfin_k(const float* __restrict__ pmg,
                                              const float* __restrict__ psg,
                                              float* __restrict__ cmax,
                                              float* __restrict__ cinv) {
  long i = (long)blockIdx.x * 256 + threadIdx.x;  // b*LQ + q
  long b = i / LQ, q = i - b * LQ;
  const float* mp = pmg + (b * 16) * LQ + q;
  const float* sp = psg + (b * 16) * LQ + q;
  float m = -3e38f, s = 0.f;
#pragma unroll
  for (int t = 0; t < 16; t++) {
    float mm = mp[(long)t * LQ], ss = sp[(long)t * LQ];
    float nm = fmaxf(m, mm);
    s = s * __expf(m - nm) + ss * __expf(mm - nm);
    m = nm;
  }
  cmax[i] = m;
  cinv[i] = 1.f / s;
}

// ------------- Pq from E: Pq[q][p] = E[p][q]*exp(pmg[tile][q]-cmax[q])*cinv[q] -------------
__global__ __launch_bounds__(256) void pq_k(const half_t* __restrict__ E,
                                            half_t* __restrict__ out,
                                            const float* __restrict__ pmg,
                                            const float* __restrict__ cmax,
                                            const float* __restrict__ cinv) {
  __shared__ half_t tile[64 * 64];
  const long zb = blockIdx.z;
  const half_t* src = E + zb * (long)LP * LQ;
  half_t* dst = out + zb * (long)LQ * LP;
  const int r0 = blockIdx.y * 64, c0 = blockIdx.x * 64;
  const int tIdx = r0 >> 7;
  const int t = threadIdx.x;
  const int cl = (t & 15) * 4;
  const int rl = t >> 4;
  f32x4 tm = *(const f32x4*)(pmg + ((long)zb * 16 + tIdx) * LQ + c0 + cl);
  f32x4 cm = *(const f32x4*)(cmax + (long)zb * LQ + c0 + cl);
  f32x4 ci = *(const f32x4*)(cinv + (long)zb * LQ + c0 + cl);
  float sc[4];
#pragma unroll
  for (int j = 0; j < 4; j++) sc[j] = __expf(tm[j] - cm[j]) * ci[j];
#pragma unroll
  for (int rr = 0; rr < 4; rr++) {
    int r = rr * 16 + rl;
    f16x4 v = *(const f16x4*)(src + (long)(r0 + r) * LQ + c0 + cl);
#pragma unroll
    for (int j = 0; j < 4; j++) {
      float x = (float)v[j] * sc[j];
      int c = cl + j;
      tile[c * 64 + (r ^ (((c >> 3) & 7) << 3))] = (half_t)x;
    }
  }
  __syncthreads();
  const int c = t >> 2;
  const int rch = (t & 3) * 16;
  const int m = (c >> 3) & 7;
  const int B0 = c * 64 + (rch ^ ((m << 3) & 48));
  const int hi = (m & 1) << 3;
  f16x8 g0 = *(const f16x8*)&tile[B0 + hi];
  f16x8 g1 = *(const f16x8*)&tile[B0 + (8 ^ hi)];
  half_t* dp = dst + (long)(c0 + c) * LP + r0 + rch;
  *(f16x8*)dp = g0;
  *(f16x8*)(dp + 8) = g1;
}

// ---------------- staging: [ROWS][32] f16 via gload_lds; k-slot XOR (row>>1)&3 ----------------
template<int ROWS>
__device__ __forceinline__ void stage_op(const half_t* src, int ld,
                                         half_t* lds_base, int wid, int lane) {
  const int goff = (((lane & 3) ^ ((lane >> 3) & 3)) << 3);
#pragma unroll
  for (int j = 0; j < ROWS / 128; ++j) {
    int row = j * 128 + wid * 16 + (lane >> 2);
    const half_t* g = src + (long)row * ld + goff;
    __builtin_amdgcn_global_load_lds((cg_void*)g,
        (lds_void*)(lds_base + j * 4096 + wid * 512), 16, 0, 0);
  }
}

__device__ __forceinline__ void xcd_swz(long lid, long nwg, long& out) {
  const long q8 = nwg >> 3, r8 = nwg & 7;
  const long xcd = lid & 7, rest = lid >> 3;
  out = (xcd < r8 ? xcd * (q8 + 1) : r8 * (q8 + 1) + (xcd - r8) * q8) + rest;
}

// ---------------- fused att GEMM (32x32x16) + dual softmax prep ----------------
// 128x512 tile (full LQ), 8 waves 2x4, 3 LDS buffers, counted vmcnt (r7 ordering).
__global__ __launch_bounds__(512, 2) void attf_k(
    const half_t* __restrict__ Ap,   // p16 [B][LP][HH]
    const half_t* __restrict__ Bp,   // qpj16 [B][LQ][HH]
    half_t* __restrict__ PpO,        // [B][LP][LQ]
    half_t* __restrict__ EO,         // [B][LP][LQ]
    float* __restrict__ pmg, float* __restrict__ psg) {
  __shared__ __align__(16) half_t As[3 * 4096];
  __shared__ __align__(16) half_t Bs[3 * 16384];
  __shared__ float rmL[4][128];
  __shared__ float cmL[2][512];
  __shared__ float rsL[4][128];
  __shared__ float csL[2][512];

  const int nby = gridDim.y;  // 16
  long lid;
  xcd_swz(blockIdx.y + (long)nby * blockIdx.z, (long)nby * gridDim.z, lid);
  const int by = (int)(lid % nby);
  const int bz = (int)(lid / nby);

  const int t0 = threadIdx.x;
  const int lane = t0 & 63;
  const int wid = t0 >> 6;
  const int wm = wid >> 2, wn = wid & 3;
  const int m0 = by * 128;

  const half_t* Abase = Ap + ((long)bz * LP + m0) * HH;
  const half_t* Bbase = Bp + (long)bz * LQ * HH;

  const int c5 = lane & 31, hi = lane >> 5;
  const int sx = (c5 >> 1) & 3;
  const int ofs0 = c5 * 32 + ((hi ^ sx) << 3);
  const int ofs1 = c5 * 32 + (((2 | hi) ^ sx) << 3);

  f32x16 acc[2][4] = {};
  const int NT = HH / 32;   // 32

#pragma unroll
  for (int tt = 0; tt < 2; ++tt) {
    stage_op<128>(Abase + tt * 32, HH, As + tt * 4096, wid, lane);
    stage_op<512>(Bbase + tt * 32, HH, Bs + tt * 16384, wid, lane);
  }

  for (int t = 0; t < NT; ++t) {
    if (t + 1 < NT) asm volatile("s_waitcnt vmcnt(5)" ::: "memory");
    else            asm volatile("s_waitcnt vmcnt(0)" ::: "memory");
    __builtin_amdgcn_s_barrier();
    asm volatile("" ::: "memory");

    const half_t* Au = As + (t % 3) * 4096;
    const half_t* Bu = Bs + (t % 3) * 16384;
    f16x8 af[2][2], bf[4][2];
#pragma unroll
    for (int mf = 0; mf < 2; ++mf) {
      const half_t* p = Au + (wm * 64 + mf * 32) * 32;
      af[mf][0] = *(const f16x8*)(p + ofs0);
      af[mf][1] = *(const f16x8*)(p + ofs1);
    }
#pragma unroll
    for (int nf = 0; nf < 4; ++nf) {
      const half_t* p = Bu + (wn * 128 + nf * 32) * 32;
      bf[nf][0] = *(const f16x8*)(p + ofs0);
      bf[nf][1] = *(const f16x8*)(p + ofs1);
    }
    if (t + 2 < NT) {
      const int u2 = (t + 2) % 3;
      stage_op<128>(Abase + (t + 2) * 32, HH, As + u2 * 4096, wid, lane);
      stage_op<512>(Bbase + (t + 2) * 32, HH, Bs + u2 * 16384, wid, lane);
    }
    __builtin_amdgcn_s_setprio(1);
#pragma unroll
    for (int mf = 0; mf < 2; ++mf)
#pragma unroll
      for (int nf = 0; nf < 4; ++nf) {
        acc[mf][nf] = __builtin_amdgcn_mfma_f32_32x32x16_f16(af[mf][0], bf[nf][0], acc[mf][nf], 0, 0, 0);
        acc[mf][nf] = __builtin_amdgcn_mfma_f32_32x32x16_f16(af[mf][1], bf[nf][1], acc[mf][nf], 0, 0, 0);
      }
    __builtin_amdgcn_s_setprio(0);
  }

  // ===== pass1: row max (512 cols) / col max (128 rows); pmg write =====
  float rmv[2][16], cmv[4];
#pragma unroll
  for (int m = 0; m < 2; ++m)
#pragma unroll
    for (int r = 0; r < 16; ++r) {
      float v = fmaxf(fmaxf(acc[m][0][r], acc[m][1][r]), fmaxf(acc[m][2][r], acc[m][3][r]));
#pragma unroll
      for (int o = 1; o < 32; o <<= 1) v = fmaxf(v, __shfl_xor(v, o, 64));
      rmv[m][r] = v;
    }
#pragma unroll
  for (int n = 0; n < 4; ++n) {
    float v = acc[0][n][0];
#pragma unroll
    for (int m = 0; m < 2; ++m)
#pragma unroll
      for (int r = 0; r < 16; ++r) v = fmaxf(v, acc[m][n][r]);
    v = fmaxf(v, __shfl_xor(v, 32, 64));
    cmv[n] = v;
  }
  if (c5 < 16) {
#pragma unroll
    for (int m = 0; m < 2; ++m)
      rmL[wn][wm * 64 + m * 32 + (c5 & 3) + 8 * (c5 >> 2) + 4 * hi] = rmv[m][c5];
  }
  if (hi == 0) {
#pragma unroll
    for (int n = 0; n < 4; ++n) cmL[wm][wn * 128 + n * 32 + c5] = cmv[n];
  }
  __syncthreads();
  if (t0 < 128)
    rmL[0][t0] = fmaxf(fmaxf(rmL[0][t0], rmL[1][t0]), fmaxf(rmL[2][t0], rmL[3][t0]));
  {
    float cm2 = fmaxf(cmL[0][t0 & 511], cmL[1][t0 & 511]);
    cmL[0][t0 & 511] = cm2;
    pmg[((long)bz * 16 + by) * LQ + (t0 & 511)] = cm2;
  }
  __syncthreads();
#pragma unroll
  for (int m = 0; m < 2; ++m)
#pragma unroll
    for (int r = 0; r < 16; ++r)
      rmv[m][r] = rmL[0][wm * 64 + m * 32 + (r & 3) + 8 * (r >> 2) + 4 * hi];
#pragma unroll
  for (int n = 0; n < 4; ++n) cmv[n] = cmL[0][wn * 128 + n * 32 + c5];

  // ===== pass2 (merged): one exp pass -> E store + col sums + row sums; acc <- p =====
  half_t* EB = EO + (long)bz * LP * LQ;
  float csW[4] = {0.f, 0.f, 0.f, 0.f};
  float rowS[2][16];
#pragma unroll
  for (int m = 0; m < 2; ++m)
#pragma unroll
    for (int r = 0; r < 16; ++r) {
      long grow = (long)(m0 + wm * 64 + m * 32 + (r & 3) + 8 * (r >> 2) + 4 * hi) * LQ;
      float s = 0.f;
#pragma unroll
      for (int n = 0; n < 4; ++n) {
        float a = acc[m][n][r];
        float e = __expf(a - cmv[n]);
        float p = __expf(a - rmv[m][r]);
        csW[n] += e;
        EB[grow + wn * 128 + n * 32 + c5] = (half_t)e;
        acc[m][n][r] = p;
        s += p;
      }
#pragma unroll
      for (int o = 1; o < 32; o <<= 1) s += __shfl_xor(s, o, 64);
      rowS[m][r] = s;
    }
#pragma unroll
  for (int n = 0; n < 4; ++n) csW[n] += __shfl_xor(csW[n], 32, 64);
  if (c5 < 16) {
#pragma unroll
    for (int m = 0; m < 2; ++m)
      rsL[wn][wm * 64 + m * 32 + (c5 & 3) + 8 * (c5 >> 2) + 4 * hi] = rowS[m][c5];
  }
  if (hi == 0) {
#pragma unroll
    for (int n = 0; n < 4; ++n) csL[wm][wn * 128 + n * 32 + c5] = csW[n];
  }
  __syncthreads();
  if (t0 < 128)
    rsL[0][t0] = 1.f / (rsL[0][t0] + rsL[1][t0] + rsL[2][t0] + rsL[3][t0]);
  psg[((long)bz * 16 + by) * LQ + (t0 & 511)] = csL[0][t0 & 511] + csL[1][t0 & 511];
  __syncthreads();

  // ===== pass3: Pp = p * rinv =====
  half_t* PpB = PpO + (long)bz * LP * LQ;
#pragma unroll
  for (int m = 0; m < 2; ++m)
#pragma unroll
    for (int r = 0; r < 16; ++r) {
      int row = wm * 64 + m * 32 + (r & 3) + 8 * (r >> 2) + 4 * hi;
      long grow = (long)(m0 + row) * LQ;
      float ri = rsL[0][row];
#pragma unroll
      for (int n = 0; n < 4; ++n)
        PpB[grow + wn * 128 + n * 32 + c5] = (half_t)(acc[m][n][r] * ri);
    }
}

// ---------------- pipelined TN MFMA GEMM (32x32x16), BMx256 tile (r7 structure) ----------------
template<int MODE, int BM>
__global__ __launch_bounds__(512, 2) void gemm_k(
    const half_t* __restrict__ Ap, const half_t* __restrict__ Bp, void* __restrict__ Cp,
    const float* __restrict__ bias,
    int lda, int ldb, int ldc, int K,
    long sA, long sB, long sC) {
  constexpr int NMF = BM / 64;
  constexpr int AS = BM * 32;
  __shared__ __align__(16) half_t As[4 * AS];
  __shared__ __align__(16) half_t Bs[4 * 8192];

  const int nbx = gridDim.x, nby = gridDim.y;
  long lid;
  xcd_swz(blockIdx.x + (long)nbx * (blockIdx.y + (long)nby * blockIdx.z),
          (long)nbx * nby * gridDim.z, lid);
  const int bx = (int)(lid % nbx);
  const long tmp = lid / nbx;
  const int by = (int)(tmp % nby);
  const int bz = (int)(tmp / nby);

  const int t0 = threadIdx.x;
  const int lane = t0 & 63;
  const int wid = t0 >> 6;
  const int wm = wid >> 2, wn = wid & 3;
  const int m0 = by * BM, n0 = bx * 256;

  const half_t* Abase = Ap + sA * bz + (long)m0 * lda;
  const half_t* Bbase = Bp + sB * bz + (long)n0 * ldb;

  const int c5 = lane & 31, hi = lane >> 5;
  const int sx = (c5 >> 1) & 3;
  const int ofs0 = c5 * 32 + ((hi ^ sx) << 3);
  const int ofs1 = c5 * 32 + (((2 | hi) ^ sx) << 3);

  f32x16 acc[NMF][2] = {};
  const int NT = K >> 5;

#pragma unroll
  for (int tt = 0; tt < 3; ++tt) {
    stage_op<BM>(Abase + tt * 32, lda, As + tt * AS, wid, lane);
    stage_op<256>(Bbase + tt * 32, ldb, Bs + tt * 8192, wid, lane);
  }

  for (int t = 0; t < NT; ++t) {
    if (t + 2 < NT) {
      if constexpr (BM == 256) asm volatile("s_waitcnt vmcnt(8)" ::: "memory");
      else                     asm volatile("s_waitcnt vmcnt(6)" ::: "memory");
    } else if (t + 1 < NT) {
      if constexpr (BM == 256) asm volatile("s_waitcnt vmcnt(4)" ::: "memory");
      else                     asm volatile("s_waitcnt vmcnt(3)" ::: "memory");
    } else {
      asm volatile("s_waitcnt vmcnt(0)" ::: "memory");
    }
    __builtin_amdgcn_s_barrier();
    asm volatile("" ::: "memory");

    const half_t* Au = As + (t & 3) * AS;
    const half_t* Bu = Bs + (t & 3) * 8192;
    f16x8 af[NMF][2], bf[2][2];
#pragma unroll
    for (int mf = 0; mf < NMF; ++mf) {
      const half_t* p = Au + (wm * (BM / 2) + mf * 32) * 32;
      af[mf][0] = *(const f16x8*)(p + ofs0);
      af[mf][1] = *(const f16x8*)(p + ofs1);
    }
#pragma unroll
    for (int nf = 0; nf < 2; ++nf) {
      const half_t* p = Bu + (wn * 64 + nf * 32) * 32;
      bf[nf][0] = *(const f16x8*)(p + ofs0);
      bf[nf][1] = *(const f16x8*)(p + ofs1);
    }
    if (t + 3 < NT) {
      const int u3 = (t + 3) & 3;
      stage_op<BM>(Abase + (t + 3) * 32, lda, As + u3 * AS, wid, lane);
      stage_op<256>(Bbase + (t + 3) * 32, ldb, Bs + u3 * 8192, wid, lane);
    }
    __builtin_amdgcn_s_setprio(1);
#pragma unroll
    for (int mf = 0; mf < NMF; ++mf)
#pragma unroll
      for (int nf = 0; nf < 2; ++nf) {
        acc[mf][nf] = __builtin_amdgcn_mfma_f32_32x32x16_f16(af[mf][0], bf[nf][0], acc[mf][nf], 0, 0, 0);
        acc[mf][nf] = __builtin_amdgcn_mfma_f32_32x32x16_f16(af[mf][1], bf[nf][1], acc[mf][nf], 0, 0, 0);
      }
    __builtin_amdgcn_s_setprio(0);
  }

  // ---- epilogue: col=lane&31, row=(r&3)+8*(r>>2)+4*hi ----
#pragma unroll
  for (int nf = 0; nf < 2; ++nf) {
    int col = n0 + wn * 64 + nf * 32 + c5;
    float bv = 0.f;
    if constexpr (MODE == M_QPROJ) bv = bias[col];
#pragma unroll
    for (int mf = 0; mf < NMF; ++mf) {
      int rbase = m0 + wm * (BM / 2) + mf * 32 + 4 * hi;
#pragma unroll
      for (int r = 0; r < 16; ++r) {
        int row = rbase + (r & 3) + 8 * (r >> 2);
        if constexpr (MODE == M_QPROJ)
          ((half_t*)Cp)[(long)row * ldc + col] = (half_t)(acc[mf][nf][r] + bv);
        else
          ((float*)Cp)[sC * bz + (long)row * ldc + col] = acc[mf][nf][r];
      }
    }
  }
}

extern "C" void kernel_launch(void* const* d_in, const int* in_sizes, int n_in,
                              void* d_out, int out_size, void* d_ws, size_t ws_size,
                              hipStream_t stream) {
  const float* p_enc = (const float*)d_in[0];  // [B, LP, H]
  const float* q_enc = (const float*)d_in[1];  // [B, LQ, H]
  const float* Gw    = (const float*)d_in[2];  // [H, H]
  const float* Gb    = (const float*)d_in[3];  // [H]
  float* m_p = (float*)d_out;
  float* m_q = m_p + (long)BB * LP * HH;

  // workspace carve (~548 MB, ws is ~1.25 GiB)
  half_t* w16   = (half_t*)d_ws;                    // HH*HH
  half_t* q16   = w16 + (long)HH * HH;              // BB*LQ*HH
  half_t* qT16  = q16 + (long)BB * LQ * HH;         // BB*HH*LQ
  half_t* qpj16 = qT16 + (long)BB * HH * LQ;        // BB*LQ*HH
  half_t* p16   = qpj16 + (long)BB * LQ * HH;       // BB*LP*HH
  half_t* pT16  = p16 + (long)BB * LP * HH;         // BB*HH*LP
  half_t* Pp    = pT16 + (long)BB * HH * LP;        // BB*LP*LQ
  half_t* Ebuf  = Pp + (long)BB * LP * LQ;          // BB*LP*LQ
  half_t* Pq    = Ebuf + (long)BB * LP * LQ;        // BB*LQ*LP
  float*  cmaxb = (float*)(Pq + (long)BB * LQ * LP);
  float*  cinvb = cmaxb + (long)BB * LQ;
  float*  pmg   = cinvb + (long)BB * LQ;            // BB*16*LQ
  float*  psg   = pmg + (long)BB * 16 * LQ;         // BB*16*LQ

  cvt16_k<<<HH * HH / 1024, 256, 0, stream>>>(Gw, w16);

  // q16 + qT16 (one read of q_enc)
  dualcvt_k<<<dim3(HH / 64, LQ / 64, BB), 256, 0, stream>>>(q_enc, q16, qT16, LQ, HH);

  // qproj16 = q16 . w16^T + Gb   (M=BB*LQ=16384, N=HH, K=HH)
  gemm_k<M_QPROJ, 256><<<dim3(HH / 256, BB * LQ / 256, 1), 512, 0, stream>>>(
      q16, w16, qpj16, Gb, HH, HH, HH, HH, 0, 0, 0);

  // p16 + pT16 (one read of p_enc)
  dualcvt_k<<<dim3(HH / 64, LP / 64, BB), 256, 0, stream>>>(p_enc, p16, pT16, LP, HH);

  // fused att GEMM: Pp, E, col partials
  attf_k<<<dim3(1, LP / 128, BB), 512, 0, stream>>>(p16, qpj16, Pp, Ebuf, pmg, psg);

  // finalize col stats; build Pq from E
  cfin_k<<<BB * LQ / 256, 256, 0, stream>>>(pmg, psg, cmaxb, cinvb);
  pq_k<<<dim3(LQ / 64, LP / 64, BB), 256, 0, stream>>>(Ebuf, Pq, pmg, cmaxb, cinvb);

  // m_p = Pp @ qT16^T   (M=LP, N=HH, K=LQ)
  gemm_k<M_OUT32, 256><<<dim3(HH / 256, LP / 256, BB), 512, 0, stream>>>(
      Pp, qT16, m_p, nullptr, LQ, LQ, HH, LQ,
      (long)LP * LQ, (long)HH * LQ, (long)LP * HH);

  // m_q = Pq @ pT16^T   (M=LQ, N=HH, K=LP)  — now BM=256
  gemm_k<M_OUT32, 256><<<dim3(HH / 256, LQ / 256, BB), 512, 0, stream>>>(
      Pq, pT16, m_q, nullptr, LP, LP, HH, LP,
      (long)LQ * LP, (long)HH * LP, (long)LQ * HH);
}